// Round 1
// baseline (823.338 us; speedup 1.0000x reference)
//
#include <hip/hip_runtime.h>
#include <hip/hip_bf16.h>
#include <cstddef>

// Problem constants
#define BATCH 65536
#define HDIM  256
#define NGATE 7
#define BH    ((size_t)BATCH * HDIM)

typedef __bf16 bf16x8 __attribute__((ext_vector_type(8)));
typedef __bf16 bf16x4 __attribute__((ext_vector_type(4)));
typedef float  f32x4  __attribute__((ext_vector_type(4)));

// ---------------------------------------------------------------------------
// Kernel 1: convert W (G*H*H fp32) -> bf16 in workspace, same (g,o,h) layout.
// ---------------------------------------------------------------------------
__global__ void __launch_bounds__(256) cvt_w_kernel(const float* __restrict__ W,
                                                    __bf16* __restrict__ Wb) {
    int i = (blockIdx.x * 256 + threadIdx.x) * 4;
    float4 v = *(const float4*)(W + i);
    bf16x4 r;
    r[0] = (__bf16)v.x; r[1] = (__bf16)v.y; r[2] = (__bf16)v.z; r[3] = (__bf16)v.w;
    *(bf16x4*)(Wb + i) = r;
}

// ---------------------------------------------------------------------------
// Fast device math (bf16-level tolerance)
// ---------------------------------------------------------------------------
__device__ __forceinline__ float sigmoidf_(float x) {
    return __builtin_amdgcn_rcpf(1.0f + __expf(-x));
}
__device__ __forceinline__ float tanhf_(float x) {
    return 1.0f - 2.0f * __builtin_amdgcn_rcpf(1.0f + __expf(2.0f * x));
}
__device__ __forceinline__ float softplusf_(float x) {
    return fmaxf(x, 0.0f) + __logf(1.0f + __expf(-fabsf(x)));
}

// ---------------------------------------------------------------------------
// Kernel 2: swapped-operand fused GEMM + CT-LSTM epilogue.
//
// MFMA roles: A = W[g] (M = o), B = h_ti (N = batch).
//   A[m][k]: m = lane&15 (o), k = quad*8 + j  -> Wb[g][o0+col][k0..k0+8) 16B bf16
//   B[k][n]: n = lane&15 (batch), k = quad*8+j -> h[b][k0..k0+8) converted once,
//            K-resident in 8x bf16x8 = 32 VGPR
//   C[row][col]: col = batch (lane&15), row = o = quad*4 + reg
//     -> each lane owns 4 CONSECUTIVE o for one batch: float4 epilogue I/O.
//
// Per wave: 16 batches x 16 o-tile x 7 gates, acc = 7 x f32x4 = 28 VGPR,
// o-loop x16. Block = 4 waves = 64 batches, all 256 o. Grid = 1024 blocks
// = exactly 4 blocks/CU; launch_bounds(256,4) caps VGPR at 128 -> 16 waves/CU.
// ---------------------------------------------------------------------------
__global__ void __launch_bounds__(256, 4)
fused_ctlstm(const float* __restrict__ inter_times,
             const float* __restrict__ h_ti,
             const float* __restrict__ c_ti,
             const float* __restrict__ cbar,
             const __bf16* __restrict__ Wb,
             const float* __restrict__ bias,
             float* __restrict__ out) {
    const int tid  = threadIdx.x;
    const int lane = tid & 63;
    const int wave = tid >> 6;
    const int col  = lane & 15;
    const int quad = lane >> 4;

    const int b = blockIdx.x * 64 + wave * 16 + col;   // this lane's batch row
    const float dt = inter_times[b];

    // ---- Load this lane's h row once, convert fp32->bf16, keep K-resident ----
    bf16x8 bfrag[8];
    {
        const float* hp = h_ti + (size_t)b * HDIM + quad * 8;
#pragma unroll
        for (int ks = 0; ks < 8; ++ks) {
            float4 lo = *(const float4*)(hp + ks * 32);
            float4 hi = *(const float4*)(hp + ks * 32 + 4);
            bf16x8 v;
            v[0] = (__bf16)lo.x; v[1] = (__bf16)lo.y;
            v[2] = (__bf16)lo.z; v[3] = (__bf16)lo.w;
            v[4] = (__bf16)hi.x; v[5] = (__bf16)hi.y;
            v[6] = (__bf16)hi.z; v[7] = (__bf16)hi.w;
            bfrag[ks] = v;
        }
    }

#pragma unroll 1
    for (int ot = 0; ot < 16; ++ot) {
        const int o0   = ot * 16;
        const int orow = o0 + quad * 4;                 // 4 consecutive o
        const size_t idx = (size_t)b * HDIM + orow;

        // Issue the epilogue HBM loads early; latency hides under the MFMAs.
        const f32x4 ct4 = *(const f32x4*)(c_ti + idx);
        const f32x4 cb4 = *(const f32x4*)(cbar + idx);

        f32x4 acc[NGATE];
#pragma unroll
        for (int g = 0; g < NGATE; ++g) acc[g] = (f32x4){0.f, 0.f, 0.f, 0.f};

#pragma unroll
        for (int ks = 0; ks < 8; ++ks) {
            const __bf16* wp = Wb + (size_t)(o0 + col) * HDIM + ks * 32 + quad * 8;
#pragma unroll
            for (int g = 0; g < NGATE; ++g) {
                bf16x8 afrag = *(const bf16x8*)(wp + (size_t)g * HDIM * HDIM);
                acc[g] = __builtin_amdgcn_mfma_f32_16x16x32_bf16(
                    afrag, bfrag[ks], acc[g], 0, 0, 0);
            }
        }

        // Fold bias into acc (float4 loads, L1-hot, lane-uniform within quad)
#pragma unroll
        for (int g = 0; g < NGATE; ++g)
            acc[g] += *(const f32x4*)(bias + g * HDIM + orow);

        // Epilogue: per lane, 4 consecutive o for one batch -> float4 stores
        f32x4 og4, hn4, cn4, cbn4, dec4;
#pragma unroll
        for (int r = 0; r < 4; ++r) {
            const float i_g  = sigmoidf_(acc[0][r]);
            const float f_g  = sigmoidf_(acc[1][r]);
            const float o_g  = sigmoidf_(acc[2][r]);
            const float ib_g = sigmoidf_(acc[3][r]);
            const float fb_g = sigmoidf_(acc[4][r]);
            const float z    = tanhf_(acc[5][r]);
            const float dec  = softplusf_(acc[6][r]);

            const float ct = ct4[r];
            const float cb = cb4[r];

            const float c_after = cb + (ct - cb) * __expf(-dec * dt);
            og4[r]  = o_g;
            hn4[r]  = o_g * tanhf_(c_after);
            cn4[r]  = f_g * c_after + i_g * z;
            cbn4[r] = fb_g * cb + ib_g * z;
            dec4[r] = dec;
        }

        // Nontemporal: pure write streams, keep W resident in L2
        __builtin_nontemporal_store(og4,  (f32x4*)(out + idx));
        __builtin_nontemporal_store(hn4,  (f32x4*)(out + BH + idx));
        __builtin_nontemporal_store(cn4,  (f32x4*)(out + 2 * BH + idx));
        __builtin_nontemporal_store(cbn4, (f32x4*)(out + 3 * BH + idx));
        __builtin_nontemporal_store(dec4, (f32x4*)(out + 4 * BH + idx));
    }
}

// ---------------------------------------------------------------------------
extern "C" void kernel_launch(void* const* d_in, const int* in_sizes, int n_in,
                              void* d_out, int out_size, void* d_ws, size_t ws_size,
                              hipStream_t stream) {
    const float* inter_times = (const float*)d_in[0];
    const float* h_ti        = (const float*)d_in[1];
    const float* c_ti        = (const float*)d_in[2];
    const float* cbar        = (const float*)d_in[3];
    const float* W           = (const float*)d_in[4];
    const float* bias        = (const float*)d_in[5];
    float* out = (float*)d_out;

    __bf16* Wb = (__bf16*)d_ws;  // needs G*H*H*2 = 917504 bytes

    cvt_w_kernel<<<(NGATE * HDIM * HDIM) / (256 * 4), 256, 0, stream>>>(W, Wb);

    fused_ctlstm<<<BATCH / 64, 256, 0, stream>>>(inter_times, h_ti, c_ti, cbar,
                                                 Wb, bias, out);
}